// Round 9
// baseline (508.925 us; speedup 1.0000x reference)
//
#include <hip/hip_runtime.h>
#include <hip/hip_bf16.h>

// InterestEvolve: attention-modulated GRU scan. B=2048, T=200, D=128, U=128.
//
// R17: the CLEAN 4-wave x 32-gatecol experiment (halve the post-barrier LDS
// herd). After each barrier all waves burst-read byte-identical fragments;
// at 8 waves that is 96 b128 reads/step/CU (~1150cy + 448 conflict-cy) at the
// head of every region's dependency chain. 4 waves halves it to 48.
// Prior attempts were confounded: R9/R10 bundled global-direct x (R11 showed
// that alone costs ~+1.1us/step); R13 bundled producer waves under a 128-VGPR
// cap (spill: WRITE_SIZE 1.8->22MB). This run isolates the wave-width change:
//  - 4 waves (256 thr), launch_bounds(256,1): 512-VGPR budget, no spill.
//  - x/Att staged in LDS (R8/R14 staging map adapted to 256 threads).
//  - R14's async chunk prefetch (px[24] regs, publish at chunk boundary).
//  - lgkm-only hardened barriers (validated R10-R16).
//  - R16's xf-read hoist kept (tail would be fully exposed at 1 wave/SIMD).
// Numerics: same accumulation order as R8/R14 (absmax 0.0044 expected).
// 128 blocks x 256 threads.

#define T_LEN 200
#define D_DIM 128
#define U_DIM 128
#define BM    16
#define CH    12
#define NCH   ((T_LEN + CH - 1) / CH)   // 17, last chunk L=8
#define KCS   136          // ushorts per kchunk slot-row: 16 batch*8 + 8 pad
#define XSTEP (16 * KCS)   // ushorts per staged step (2176)

typedef __attribute__((ext_vector_type(8))) short bf16x8;
typedef __attribute__((ext_vector_type(4))) float f32x4;
typedef __attribute__((ext_vector_type(4))) unsigned int uint4v;

#define MFMA __builtin_amdgcn_mfma_f32_16x16x32_bf16

static __device__ __forceinline__ unsigned short f2bf(float f) {
    unsigned int u = __builtin_bit_cast(unsigned int, f);
    u += 0x7fffu + ((u >> 16) & 1u);       // round-to-nearest-even
    return (unsigned short)(u >> 16);
}
static __device__ __forceinline__ unsigned int pkbf2(float a, float b) {
    float2 t; t.x = a; t.y = b;
    __hip_bfloat162 v = __float22bfloat162_rn(t);   // v_cvt_pk_bf16_f32
    unsigned int u; __builtin_memcpy(&u, &v, 4);
    return u;
}
static __device__ __forceinline__ uint4v pack8u(float4 lo, float4 hi) {
    uint4v v;
    v[0] = pkbf2(lo.x, lo.y); v[1] = pkbf2(lo.z, lo.w);
    v[2] = pkbf2(hi.x, hi.y); v[3] = pkbf2(hi.z, hi.w);
    return v;
}
static __device__ __forceinline__ float fast_exp2(float x) {
#if __has_builtin(__builtin_amdgcn_exp2f)
    return __builtin_amdgcn_exp2f(x);
#else
    return exp2f(x);
#endif
}
static __device__ __forceinline__ float fast_rcp(float x) {
#if __has_builtin(__builtin_amdgcn_rcpf)
    return __builtin_amdgcn_rcpf(x);
#else
    return 1.0f / x;
#endif
}
// Barrier waiting ONLY on LDS ops; prefetch global loads stay in flight.
// sched_barrier(0) on both sides pins ds ops across it (rule #18).
static __device__ __forceinline__ void block_sync_lds() {
    asm volatile("s_waitcnt lgkmcnt(0)" ::: "memory");
    __builtin_amdgcn_sched_barrier(0);
    __builtin_amdgcn_s_barrier();
    __builtin_amdgcn_sched_barrier(0);
}

__global__ __launch_bounds__(256, 1)
void gru_scan_kernel(const float* __restrict__ X,    // (B,T,D)
                     const float* __restrict__ Att,  // (B,T,1)
                     const float* __restrict__ Wu, const float* __restrict__ bu,
                     const float* __restrict__ Wr, const float* __restrict__ br,
                     const float* __restrict__ Wh, const float* __restrict__ bh,
                     float* __restrict__ out)        // (B,U)
{
    __shared__ __align__(16) unsigned short x_sm[CH * XSTEP];  // 52224 B
    __shared__ __align__(16) unsigned short h_bf[XSTEP];       // 4352 B
    __shared__ __align__(16) unsigned short rh_bf[XSTEP];      // 4352 B
    __shared__ float a_sm[CH * BM];                            // 768 B

    const int tid  = threadIdx.x;
    const int wave = tid >> 6;    // 0..3, owns gatecols [32*wave, 32*wave+32)
    const int lane = tid & 63;
    const int q    = lane >> 4;
    const int ln   = lane & 15;
    const int b0   = blockIdx.x * BM;

    const float INVLN2 = 1.4426950408889634f;

    // ---- Weight A-fragments: 2 col-tiles x 8 k-tiles per matrix (192 VGPR),
    // bf16, ln2-prescaled. lane holds gatecol m = ln (tile base 32w+16tl),
    // k = 32*kt + 8*q + j. GEMM1 k: [h|x] rows. GEMM2 k: [x | r*h] rows.
    bf16x8 wu[2][8], wr[2][8], wh[2][8];
    f32x4 nbu[2], nbr[2], bh2[2];                   // C-operand bias preload
    #pragma unroll
    for (int tl = 0; tl < 2; ++tl) {
        const int tb = 32 * wave + 16 * tl;
        const int c  = tb + ln;
        const f32x4 bu4 = *(const f32x4*)&bu[tb + 4 * q];
        const f32x4 br4 = *(const f32x4*)&br[tb + 4 * q];
        const f32x4 bh4 = *(const f32x4*)&bh[tb + 4 * q];
        #pragma unroll
        for (int r = 0; r < 4; ++r) {
            nbu[tl][r] = -bu4[r] * INVLN2;
            nbr[tl][r] = -br4[r] * INVLN2;
            bh2[tl][r] = 2.0f * bh4[r] * INVLN2;
        }
        #pragma unroll
        for (int kt = 0; kt < 8; ++kt) {
            const int k0 = 32 * kt + 8 * q;
            bf16x8 vu, vr, vh;
            #pragma unroll
            for (int j = 0; j < 8; ++j) {
                vu[j] = (short)f2bf(Wu[(k0 + j) * U_DIM + c] * -INVLN2);
                vr[j] = (short)f2bf(Wr[(k0 + j) * U_DIM + c] * -INVLN2);
                vh[j] = (short)f2bf(Wh[(k0 + j) * U_DIM + c] * (2.0f * INVLN2));
            }
            wu[tl][kt] = vu; wr[tl][kt] = vr; wh[tl][kt] = vh;
        }
    }

    float hreg[2][4] = {{0.f,0.f,0.f,0.f},{0.f,0.f,0.f,0.f}};

    // ---- clear ALL of h_bf / rh_bf (1088 uints each, incl. padding) ----
    {
        unsigned int* hz = (unsigned int*)h_bf;
        unsigned int* rz = (unsigned int*)rh_bf;
        for (int i = tid; i < XSTEP / 2; i += 256) { hz[i] = 0; rz[i] = 0; }
    }

    // staging map (256 thr): thread = (srow=(tid>>4)&15, cs=tid&15), covers
    // all CH steps itself (2 float4 per step).
    const int srow = (tid >> 4) & 15;
    const int cs   = tid & 15;
    const float* xbase = X + (size_t)(b0 + srow) * T_LEN * D_DIM + cs * 8;

    // ---- prologue: stage chunk 0 synchronously ----
    {
        float4 p0[2 * CH];
        #pragma unroll
        for (int w = 0; w < CH; ++w) {
            const float* src = xbase + (size_t)w * D_DIM;   // t = w < T_LEN
            p0[2 * w]     = *(const float4*)(src);
            p0[2 * w + 1] = *(const float4*)(src + 4);
        }
        float a_px = 0.0f;
        if (tid < BM * CH)
            a_px = Att[(size_t)(b0 + (tid & 15)) * T_LEN + (tid >> 4)];
        #pragma unroll
        for (int w = 0; w < CH; ++w)
            *(uint4v*)&x_sm[w * XSTEP + cs * KCS + srow * 8] =
                pack8u(p0[2 * w], p0[2 * w + 1]);
        if (tid < BM * CH) a_sm[tid] = a_px;
    }
    __syncthreads();

    const int c8base = (4 * wave) * KCS + ln * 8 + (q & 1) * 4;
    const int c8q    = (q >> 1) * KCS;

    int t0 = 0;
    for (int ch = 0; ch < NCH; ++ch) {
        const int L  = (t0 + CH <= T_LEN) ? CH : (T_LEN - t0);
        const bool st = (ch + 1 < NCH);

        // ---- ISSUE next-chunk loads now (published at chunk boundary).
        // ~12 steps of scan hide the HBM latency; lgkm-only barriers keep
        // these in flight.
        float4 px[2 * CH];
        float av = 0.0f;
        if (st) {
            const int tn0 = t0 + CH;
            #pragma unroll
            for (int w = 0; w < CH; ++w) {
                int t = tn0 + w;
                t = (t < T_LEN) ? t : (T_LEN - 1);        // clamped, branchless
                const float* src = xbase + (size_t)t * D_DIM;
                px[2 * w]     = *(const float4*)(src);
                px[2 * w + 1] = *(const float4*)(src + 4);
            }
            if (tid < BM * CH) {
                int ta = tn0 + (tid >> 4);
                ta = (ta < T_LEN) ? ta : (T_LEN - 1);
                av = Att[(size_t)(b0 + (tid & 15)) * T_LEN + ta];
            }
        }

        // ---- x-part accumulators for step 0 (bias preloaded into C) ----
        f32x4 acc_r[2], acc_u[2], acc_h[2];
        {
            bf16x8 xf[4];
            #pragma unroll
            for (int kt = 0; kt < 4; ++kt)
                xf[kt] = *(const bf16x8*)&x_sm[(4 * kt + q) * KCS + ln * 8];
            #pragma unroll
            for (int tl = 0; tl < 2; ++tl) {
                acc_r[tl] = nbr[tl]; acc_u[tl] = nbu[tl]; acc_h[tl] = bh2[tl];
                #pragma unroll
                for (int kt = 0; kt < 4; ++kt) {
                    acc_r[tl] = MFMA(wr[tl][kt + 4], xf[kt], acc_r[tl], 0, 0, 0);
                    acc_u[tl] = MFMA(wu[tl][kt + 4], xf[kt], acc_u[tl], 0, 0, 0);
                    acc_h[tl] = MFMA(wh[tl][kt],     xf[kt], acc_h[tl], 0, 0, 0);
                }
            }
        }

        for (int s = 0; s < L; ++s) {
            // ---------- region 1: h-parts (r critical, 2+2 split) ----------
            bf16x8 hf[4];     // identical fragments for all waves
            #pragma unroll
            for (int kt = 0; kt < 4; ++kt)
                hf[kt] = *(const bf16x8*)&h_bf[(4 * kt + q) * KCS + ln * 8];
            const float a_att = a_sm[s * BM + ln];

            f32x4 ra[2], rb[2];
            #pragma unroll
            for (int tl = 0; tl < 2; ++tl) {
                ra[tl] = acc_r[tl]; rb[tl] = (f32x4)0.0f;
                ra[tl] = MFMA(wr[tl][0], hf[0], ra[tl], 0, 0, 0);
                rb[tl] = MFMA(wr[tl][2], hf[2], rb[tl], 0, 0, 0);
                ra[tl] = MFMA(wr[tl][1], hf[1], ra[tl], 0, 0, 0);
                rb[tl] = MFMA(wr[tl][3], hf[3], rb[tl], 0, 0, 0);
                #pragma unroll
                for (int kt = 0; kt < 4; ++kt)
                    acc_u[tl] = MFMA(wu[tl][kt], hf[kt], acc_u[tl], 0, 0, 0);
            }
            #pragma unroll
            for (int tl = 0; tl < 2; ++tl) {
                float rh[4];
                #pragma unroll
                for (int r = 0; r < 4; ++r) {
                    float zr = ra[tl][r] + rb[tl][r];           // = -z_r/ln2
                    float rv = fast_rcp(1.0f + fast_exp2(zr));  // sigmoid
                    rh[r] = rv * hreg[tl][r];
                }
                uint2 wv; wv.x = pkbf2(rh[0], rh[1]); wv.y = pkbf2(rh[2], rh[3]);
                *(uint2*)&rh_bf[c8base + c8q + 2 * tl * KCS] = wv;
            }
            block_sync_lds();   // rh handoff (prefetch loads stay in flight)

            // ---------- region 2 ----------
            bf16x8 rf[4];
            #pragma unroll
            for (int kt = 0; kt < 4; ++kt)
                rf[kt] = *(const bf16x8*)&rh_bf[(4 * kt + q) * KCS + ln * 8];

            // next-step xf reads issued early (chunk-stable data; tail would
            // be fully exposed at 1 wave/SIMD otherwise)
            const bool more = (s + 1 < L);
            bf16x8 xf[4];
            if (more) {
                #pragma unroll
                for (int kt = 0; kt < 4; ++kt)
                    xf[kt] = *(const bf16x8*)&x_sm[(s + 1) * XSTEP + (4 * kt + q) * KCS + ln * 8];
            }

            // u gate (off critical path; reads acc_u BEFORE x-part overwrite)
            float uq[2][4];
            #pragma unroll
            for (int tl = 0; tl < 2; ++tl)
                #pragma unroll
                for (int r = 0; r < 4; ++r)
                    uq[tl][r] = fast_rcp(1.0f + fast_exp2(acc_u[tl][r])) * a_att;

            // candidate: rh-part (critical, 2+2 split), tanh, h update/publish
            #pragma unroll
            for (int tl = 0; tl < 2; ++tl) {
                f32x4 ha = acc_h[tl], hb = (f32x4)0.0f;
                ha = MFMA(wh[tl][4], rf[0], ha, 0, 0, 0);
                hb = MFMA(wh[tl][6], rf[2], hb, 0, 0, 0);
                ha = MFMA(wh[tl][5], rf[1], ha, 0, 0, 0);
                hb = MFMA(wh[tl][7], rf[3], hb, 0, 0, 0);
                #pragma unroll
                for (int r = 0; r < 4; ++r) {
                    float z  = ha[r] + hb[r];                               // 2*z_h/ln2
                    float hh = 1.0f - 2.0f * fast_rcp(1.0f + fast_exp2(z)); // tanh
                    float ho = hreg[tl][r];
                    hreg[tl][r] = ho + uq[tl][r] * (hh - ho);               // u*hh+(1-u)*h
                }
                uint2 wv; wv.x = pkbf2(hreg[tl][0], hreg[tl][1]);
                wv.y = pkbf2(hreg[tl][2], hreg[tl][3]);
                *(uint2*)&h_bf[c8base + c8q + 2 * tl * KCS] = wv;
            }

            // x-part accumulators for step s+1 (data already in xf registers)
            if (more) {
                #pragma unroll
                for (int tl = 0; tl < 2; ++tl) {
                    acc_r[tl] = nbr[tl]; acc_u[tl] = nbu[tl]; acc_h[tl] = bh2[tl];
                    #pragma unroll
                    for (int kt = 0; kt < 4; ++kt) {
                        acc_r[tl] = MFMA(wr[tl][kt + 4], xf[kt], acc_r[tl], 0, 0, 0);
                        acc_u[tl] = MFMA(wu[tl][kt + 4], xf[kt], acc_u[tl], 0, 0, 0);
                        acc_h[tl] = MFMA(wh[tl][kt],     xf[kt], acc_h[tl], 0, 0, 0);
                    }
                }
            }
            block_sync_lds();   // h handoff
        }

        // ---- chunk boundary: publish prefetched chunk (loads landed long ago)
        if (st) {
            #pragma unroll
            for (int w = 0; w < CH; ++w)
                *(uint4v*)&x_sm[w * XSTEP + cs * KCS + srow * 8] =
                    pack8u(px[2 * w], px[2 * w + 1]);
            if (tid < BM * CH) a_sm[tid] = av;
            __syncthreads();
        }
        t0 += CH;
    }

    // ---- store h_final: 4 consecutive gatecols per thread per tile ----
    #pragma unroll
    for (int tl = 0; tl < 2; ++tl) {
        f32x4 v;
        #pragma unroll
        for (int r = 0; r < 4; ++r) v[r] = hreg[tl][r];
        *(f32x4*)&out[(size_t)(b0 + ln) * U_DIM + 32 * wave + 16 * tl + 4 * q] = v;
    }
}

extern "C" void kernel_launch(void* const* d_in, const int* in_sizes, int n_in,
                              void* d_out, int out_size, void* d_ws, size_t ws_size,
                              hipStream_t stream) {
    const float* X   = (const float*)d_in[0];
    const float* Att = (const float*)d_in[1];
    const float* Wu  = (const float*)d_in[2];
    const float* bu  = (const float*)d_in[3];
    const float* Wr  = (const float*)d_in[4];
    const float* br  = (const float*)d_in[5];
    const float* Wh  = (const float*)d_in[6];
    const float* bh  = (const float*)d_in[7];
    float* out = (float*)d_out;

    gru_scan_kernel<<<dim3(2048 / BM), dim3(256), 0, stream>>>(
        X, Att, Wu, bu, Wr, br, Wh, bh, out);
}